// Round 1
// baseline (427.146 us; speedup 1.0000x reference)
//
#include <hip/hip_runtime.h>

#define NTOK 8192
#define D 4096
#define CH 1024

typedef __attribute__((ext_vector_type(8))) short short8v;
typedef __attribute__((ext_vector_type(4))) float float4v;
typedef __attribute__((ext_vector_type(4))) unsigned short ushort4v;

static __device__ __forceinline__ unsigned short f2bf(float f) {
  unsigned int u = __float_as_uint(f);
  u += 0x7fff + ((u >> 16) & 1);   // round-to-nearest-even
  return (unsigned short)(u >> 16);
}

static __device__ __forceinline__ void async_cp16(const void* g, void* l) {
  __builtin_amdgcn_global_load_lds((__attribute__((address_space(1))) void*)g,
                                   (__attribute__((address_space(3))) void*)l,
                                   16, 0, 0);
}

// ---------------------------------------------------------------------------
// Kernel P: W_sub fp32 -> bf16 (row-major [1024][1024], K-contiguous)
// ---------------------------------------------------------------------------
__global__ __launch_bounds__(256) void prep_wsub(const float* __restrict__ Wsub,
                                                 unsigned short* __restrict__ Wb) {
  int i = blockIdx.x * 256 + threadIdx.x;     // 1M/4 float4s
  float4 v = ((const float4*)Wsub)[i];
  ushort4v o;
  o.x = f2bf(v.x); o.y = f2bf(v.y); o.z = f2bf(v.z); o.w = f2bf(v.w);
  ((ushort4v*)Wb)[i] = o;
}

// ---------------------------------------------------------------------------
// Kernel 1: gates (rms + 24 projections + sinkhorn) + x_layer (bf16)
// 8 tokens per block, 256 threads = 4 waves. Each wave owns 6 gate rows.
// ---------------------------------------------------------------------------
__global__ __launch_bounds__(256) void gates_kernel(
    const float* __restrict__ x, const float* __restrict__ rms_w,
    const float* __restrict__ Wpre, const float* __restrict__ Wpost,
    const float* __restrict__ Wres, const float* __restrict__ bpre,
    const float* __restrict__ bpost, const float* __restrict__ bres,
    const float* __restrict__ apre, const float* __restrict__ apost,
    const float* __restrict__ ares, float* __restrict__ gates_out,
    unsigned short* __restrict__ xlayer) {
  __shared__ float xbuf[8][256];
  __shared__ float logits_lds[8][24];
  __shared__ float sq_lds[8];
  __shared__ float hpre_lds[8][4];

  const int tid = threadIdx.x;
  const int lane = tid & 63;
  const int w = tid >> 6;
  const int tok0 = blockIdx.x * 8;

  const float* Wp[6];
#pragma unroll
  for (int g = 0; g < 6; ++g) {
    int gg = w * 6 + g;
    Wp[g] = (gg < 4) ? (Wpre + gg * D)
          : (gg < 8) ? (Wpost + (gg - 4) * D)
                     : (Wres + (gg - 8) * D);
  }

  float acc[6][8];
#pragma unroll
  for (int g = 0; g < 6; ++g)
#pragma unroll
    for (int t = 0; t < 8; ++t) acc[g][t] = 0.f;
  float sq0 = 0.f, sq1 = 0.f;

  for (int chk = 0; chk < 16; ++chk) {
    const int cb = chk * 256;
    // stage x chunk: 8 tokens x 256 channels
#pragma unroll
    for (int r = 0; r < 2; ++r) {
      int id = tid + r * 256;              // 0..511 float4s
      int t = id >> 6, j = id & 63;
      float4 v = *(const float4*)(x + (size_t)(tok0 + t) * D + cb + j * 4);
      *(float4*)(&xbuf[t][j * 4]) = v;
    }
    __syncthreads();
    float4 w4[6];
#pragma unroll
    for (int g = 0; g < 6; ++g) w4[g] = *(const float4*)(Wp[g] + cb + lane * 4);
    float4 r4 = *(const float4*)(rms_w + cb + lane * 4);
#pragma unroll
    for (int t = 0; t < 8; ++t) {
      float4 xv = *(const float4*)(&xbuf[t][lane * 4]);
      float ss = xv.x * xv.x + xv.y * xv.y + xv.z * xv.z + xv.w * xv.w;
      if ((t >> 1) == w) { if (t & 1) sq1 += ss; else sq0 += ss; }
      float4 xr;
      xr.x = xv.x * r4.x; xr.y = xv.y * r4.y; xr.z = xv.z * r4.z; xr.w = xv.w * r4.w;
#pragma unroll
      for (int g = 0; g < 6; ++g)
        acc[g][t] += xr.x * w4[g].x + xr.y * w4[g].y + xr.z * w4[g].z + xr.w * w4[g].w;
    }
    __syncthreads();
  }

  // wave reductions -> LDS
#pragma unroll
  for (int g = 0; g < 6; ++g)
#pragma unroll
    for (int t = 0; t < 8; ++t) {
      float v = acc[g][t];
      for (int off = 32; off > 0; off >>= 1) v += __shfl_xor(v, off, 64);
      if (lane == 0) logits_lds[t][w * 6 + g] = v;
    }
  {
    float v0 = sq0, v1 = sq1;
    for (int off = 32; off > 0; off >>= 1) {
      v0 += __shfl_xor(v0, off, 64);
      v1 += __shfl_xor(v1, off, 64);
    }
    if (lane == 0) { sq_lds[w * 2] = v0; sq_lds[w * 2 + 1] = v1; }
  }
  __syncthreads();

  // per-token scalar math: sigmoids + sinkhorn (threads 0..7)
  if (tid < 8) {
    const int t = tid;
    const int token = tok0 + t;
    float s = rsqrtf(sq_lds[t] * (1.0f / 4096.0f) + 1e-8f);
    float a_pre = apre[0], a_post = apost[0], a_res = ares[0];

    float hp[4];
    float sum_p = 1e-6f;
#pragma unroll
    for (int i = 0; i < 4; ++i) {
      float z = a_pre * (s * logits_lds[t][i]) + bpre[i];
      hp[i] = 1.0f / (1.0f + __expf(-z));
      sum_p += hp[i];
    }
    float inv_p = 1.0f / sum_p;
#pragma unroll
    for (int i = 0; i < 4; ++i) hpre_lds[t][i] = hp[i] * inv_p;

    float* go = gates_out + (size_t)token * 20;
    float hq[4];
    float sum_q = 1e-6f;
#pragma unroll
    for (int i = 0; i < 4; ++i) {
      float z = a_post * (s * logits_lds[t][4 + i]) + bpost[i];
      hq[i] = 2.0f / (1.0f + __expf(-z));
      sum_q += hq[i];
    }
    float inv_q = 1.0f / sum_q;
#pragma unroll
    for (int i = 0; i < 4; ++i) go[i] = hq[i] * inv_q;

    // sinkhorn in log domain, tau = 0.05 -> 1/tau = 20
    float Zm[16];
#pragma unroll
    for (int j = 0; j < 16; ++j)
      Zm[j] = (a_res * (s * logits_lds[t][8 + j]) + bres[j]) * 20.0f;
    float u[4] = {0, 0, 0, 0}, v[4] = {0, 0, 0, 0};
    for (int it = 0; it < 20; ++it) {
#pragma unroll
      for (int r = 0; r < 4; ++r) {
        float a0 = Zm[r * 4 + 0] + v[0], a1 = Zm[r * 4 + 1] + v[1];
        float a2 = Zm[r * 4 + 2] + v[2], a3 = Zm[r * 4 + 3] + v[3];
        float m = fmaxf(fmaxf(a0, a1), fmaxf(a2, a3));
        float sm = __expf(a0 - m) + __expf(a1 - m) + __expf(a2 - m) + __expf(a3 - m);
        u[r] = -(m + __logf(sm));
      }
#pragma unroll
      for (int c = 0; c < 4; ++c) {
        float a0 = Zm[0 + c] + u[0], a1 = Zm[4 + c] + u[1];
        float a2 = Zm[8 + c] + u[2], a3 = Zm[12 + c] + u[3];
        float m = fmaxf(fmaxf(a0, a1), fmaxf(a2, a3));
        float sm = __expf(a0 - m) + __expf(a1 - m) + __expf(a2 - m) + __expf(a3 - m);
        v[c] = -(m + __logf(sm));
      }
    }
#pragma unroll
    for (int r = 0; r < 4; ++r)
#pragma unroll
      for (int c = 0; c < 4; ++c)
        go[4 + r * 4 + c] = __expf(Zm[r * 4 + c] + u[r] + v[c]);
  }
  __syncthreads();

  // phase B: x_layer[t][c] = sum_i hpre_w[i] * x[t][i*1024+c]  (bf16 out)
#pragma unroll
  for (int t = 0; t < 8; ++t) {
    float h0 = hpre_lds[t][0], h1 = hpre_lds[t][1];
    float h2 = hpre_lds[t][2], h3 = hpre_lds[t][3];
    const size_t base = (size_t)(tok0 + t) * D;
    float4 x0 = *(const float4*)(x + base + 0 * CH + tid * 4);
    float4 x1 = *(const float4*)(x + base + 1 * CH + tid * 4);
    float4 x2 = *(const float4*)(x + base + 2 * CH + tid * 4);
    float4 x3 = *(const float4*)(x + base + 3 * CH + tid * 4);
    ushort4v o;
    o.x = f2bf(h0 * x0.x + h1 * x1.x + h2 * x2.x + h3 * x3.x);
    o.y = f2bf(h0 * x0.y + h1 * x1.y + h2 * x2.y + h3 * x3.y);
    o.z = f2bf(h0 * x0.z + h1 * x1.z + h2 * x2.z + h3 * x3.z);
    o.w = f2bf(h0 * x0.w + h1 * x1.w + h2 * x2.w + h3 * x3.w);
    *(ushort4v*)(xlayer + (size_t)(tok0 + t) * CH + tid * 4) = o;
  }
}

// ---------------------------------------------------------------------------
// Kernel 2: y = x_layer @ W_sub^T (bf16 MFMA, 128x128 tile, BK=64)
//           fused epilogue: out[t,o,c] = sum_i x[t,i,c]*Hres[o,i] + Hpost[o]*y
// ---------------------------------------------------------------------------
__global__ __launch_bounds__(256) void gemm_epi(
    const unsigned short* __restrict__ A,   // x_layer bf16 [8192][1024]
    const unsigned short* __restrict__ B,   // W_sub  bf16 [1024][1024]
    const float* __restrict__ x,            // x_streams fp32
    const float* __restrict__ gates,        // [8192][20]: Hpost_w[4], Hres[16]
    float* __restrict__ out) {
  __shared__ unsigned short Asm[128 * 64];  // 16 KB, XOR-swizzled k-quads
  __shared__ unsigned short Bsm[128 * 64];  // 16 KB
  __shared__ float gsm[128 * 20];           // 10 KB

  const int tid = threadIdx.x;
  const int lane = tid & 63;
  const int w = tid >> 6;
  const int n0 = blockIdx.x * 128;
  const int m0 = blockIdx.y * 128;

  for (int i = tid; i < 128 * 20; i += 256) gsm[i] = gates[(size_t)m0 * 20 + i];

  float4v accf[4][4];
#pragma unroll
  for (int mi = 0; mi < 4; ++mi)
#pragma unroll
    for (int ni = 0; ni < 4; ++ni) {
      accf[mi][ni].x = 0.f; accf[mi][ni].y = 0.f;
      accf[mi][ni].z = 0.f; accf[mi][ni].w = 0.f;
    }

  const int wm = (w >> 1) * 64;
  const int wn = (w & 1) * 64;
  const int srow = lane >> 3;   // staging: 8 rows per 1KB chunk
  const int sslot = lane & 7;   // 8 x 16B slots per 128B row

  for (int kt = 0; kt < 16; ++kt) {
    const int k0 = kt * 64;
#pragma unroll
    for (int i = 0; i < 4; ++i) {
      int chunk = w * 4 + i;              // 0..15
      int row = chunk * 8 + srow;         // 0..127
      int qg = sslot ^ (row & 7);         // XOR swizzle (bank spread)
      async_cp16(A + (size_t)(m0 + row) * 1024 + k0 + qg * 8,
                 (void*)(Asm + chunk * 512));
      async_cp16(B + (size_t)(n0 + row) * 1024 + k0 + qg * 8,
                 (void*)(Bsm + chunk * 512));
    }
    __syncthreads();
#pragma unroll
    for (int kk = 0; kk < 2; ++kk) {
      short8v a[4], b[4];
#pragma unroll
      for (int mi = 0; mi < 4; ++mi) {
        int row = wm + mi * 16 + (lane & 15);
        int q = (kk * 4 + (lane >> 4)) ^ (row & 7);
        a[mi] = *(const short8v*)(Asm + row * 64 + q * 8);
      }
#pragma unroll
      for (int ni = 0; ni < 4; ++ni) {
        int row = wn + ni * 16 + (lane & 15);
        int q = (kk * 4 + (lane >> 4)) ^ (row & 7);
        b[ni] = *(const short8v*)(Bsm + row * 64 + q * 8);
      }
#pragma unroll
      for (int mi = 0; mi < 4; ++mi)
#pragma unroll
        for (int ni = 0; ni < 4; ++ni)
          accf[mi][ni] = __builtin_amdgcn_mfma_f32_16x16x32_bf16(
              a[mi], b[ni], accf[mi][ni], 0, 0, 0);
    }
    __syncthreads();
  }

  // epilogue: mixing + broadcast, y stays in registers
#pragma unroll
  for (int mi = 0; mi < 4; ++mi) {
#pragma unroll
    for (int ni = 0; ni < 4; ++ni) {
      const int ch = n0 + wn + ni * 16 + (lane & 15);
#pragma unroll
      for (int r = 0; r < 4; ++r) {
        const int tl = wm + mi * 16 + (lane >> 4) * 4 + r;
        const size_t t = (size_t)(m0 + tl);
        const float* gp = gsm + tl * 20;
        const size_t xb = t * 4096 + ch;
        float x0 = x[xb], x1 = x[xb + 1024], x2 = x[xb + 2048], x3 = x[xb + 3072];
        float y = accf[mi][ni][r];
#pragma unroll
        for (int o = 0; o < 4; ++o) {
          float res = x0 * gp[4 + o * 4 + 0] + x1 * gp[4 + o * 4 + 1] +
                      x2 * gp[4 + o * 4 + 2] + x3 * gp[4 + o * 4 + 3] +
                      gp[o] * y;
          out[t * 4096 + (size_t)o * 1024 + ch] = res;
        }
      }
    }
  }
}

extern "C" void kernel_launch(void* const* d_in, const int* in_sizes, int n_in,
                              void* d_out, int out_size, void* d_ws, size_t ws_size,
                              hipStream_t stream) {
  const float* x     = (const float*)d_in[0];
  const float* rms_w = (const float*)d_in[1];
  const float* Wpre  = (const float*)d_in[2];
  const float* Wpost = (const float*)d_in[3];
  const float* Wres  = (const float*)d_in[4];
  const float* bpre  = (const float*)d_in[5];
  const float* bpost = (const float*)d_in[6];
  const float* bres  = (const float*)d_in[7];
  const float* apre  = (const float*)d_in[8];
  const float* apost = (const float*)d_in[9];
  const float* ares  = (const float*)d_in[10];
  const float* Wsub  = (const float*)d_in[11];
  float* out = (float*)d_out;

  char* ws = (char*)d_ws;
  float* gates           = (float*)ws;                    // 8192*20*4 = 640 KB
  unsigned short* Wb     = (unsigned short*)(ws + (1 << 20));  // 2 MB
  unsigned short* xlayer = (unsigned short*)(ws + (4 << 20));  // 16 MB

  prep_wsub<<<1024, 256, 0, stream>>>(Wsub, Wb);
  gates_kernel<<<1024, 256, 0, stream>>>(x, rms_w, Wpre, Wpost, Wres, bpre,
                                         bpost, bres, apre, apost, ares,
                                         gates, xlayer);
  gemm_epi<<<dim3(8, 64), 256, 0, stream>>>(xlayer, Wb, x, gates, out);
}

// Round 2
// 424.598 us; speedup vs baseline: 1.0060x; 1.0060x over previous
//
#include <hip/hip_runtime.h>

#define NTOK 8192
#define D 4096
#define CH 1024

typedef __attribute__((ext_vector_type(8))) short short8v;
typedef __attribute__((ext_vector_type(4))) float float4v;
typedef __attribute__((ext_vector_type(4))) unsigned short ushort4v;

static __device__ __forceinline__ unsigned short f2bf(float f) {
  unsigned int u = __float_as_uint(f);
  u += 0x7fff + ((u >> 16) & 1);   // round-to-nearest-even
  return (unsigned short)(u >> 16);
}

static __device__ __forceinline__ void async_cp16(const void* g, void* l) {
  __builtin_amdgcn_global_load_lds((__attribute__((address_space(1))) void*)g,
                                   (__attribute__((address_space(3))) void*)l,
                                   16, 0, 0);
}

// ---------------------------------------------------------------------------
// Kernel P: W_sub fp32 -> bf16 (row-major [1024][1024], K-contiguous)
// ---------------------------------------------------------------------------
__global__ __launch_bounds__(256) void prep_wsub(const float* __restrict__ Wsub,
                                                 unsigned short* __restrict__ Wb) {
  int i = blockIdx.x * 256 + threadIdx.x;
  float4 v = ((const float4*)Wsub)[i];
  ushort4v o;
  o.x = f2bf(v.x); o.y = f2bf(v.y); o.z = f2bf(v.z); o.w = f2bf(v.w);
  ((ushort4v*)Wb)[i] = o;
}

// ---------------------------------------------------------------------------
// Kernel 1: gates (rms + 24 projections + sinkhorn) + x_layer (bf16)
// 8 tokens per block, 256 threads = 4 waves, double-buffered async staging.
// Wave w owns gate rows w*6..w*6+5 for all 8 tokens.
// ---------------------------------------------------------------------------
__global__ __launch_bounds__(256) void gates_kernel(
    const float* __restrict__ x, const float* __restrict__ rms_w,
    const float* __restrict__ Wpre, const float* __restrict__ Wpost,
    const float* __restrict__ Wres, const float* __restrict__ bpre,
    const float* __restrict__ bpost, const float* __restrict__ bres,
    const float* __restrict__ apre, const float* __restrict__ apost,
    const float* __restrict__ ares, float* __restrict__ gates_out,
    unsigned short* __restrict__ xlayer) {
  __shared__ float xbuf[2][8][256];     // 16 KB double buffer
  __shared__ float logits_lds[8][24];
  __shared__ float sq_lds[8];
  __shared__ float s_lds[8];
  __shared__ float hpre_lds[8][4];

  const int tid = threadIdx.x;
  const int lane = tid & 63;
  const int w = tid >> 6;
  const int tok0 = blockIdx.x * 8;

  const float* Wp[6];
#pragma unroll
  for (int g = 0; g < 6; ++g) {
    int gg = w * 6 + g;
    Wp[g] = (gg < 4) ? (Wpre + gg * D)
          : (gg < 8) ? (Wpost + (gg - 4) * D)
                     : (Wres + (gg - 8) * D);
  }

  float acc[6][8];
#pragma unroll
  for (int g = 0; g < 6; ++g)
#pragma unroll
    for (int t = 0; t < 8; ++t) acc[g][t] = 0.f;
  float sq0 = 0.f, sq1 = 0.f;

  // prologue: stage chunk 0 (wave w copies token rows 2w, 2w+1; 1KB each,
  // lane i's 16B lands at base + i*16 per global_load_lds semantics)
  async_cp16(x + (size_t)(tok0 + 2 * w) * D + lane * 4, (void*)&xbuf[0][2 * w][0]);
  async_cp16(x + (size_t)(tok0 + 2 * w + 1) * D + lane * 4, (void*)&xbuf[0][2 * w + 1][0]);
  __syncthreads();

  for (int chk = 0; chk < 16; ++chk) {
    const int cb = chk * 256;
    const int cur = chk & 1;
    if (chk < 15) {   // prefetch next chunk into the other buffer
      const int nb = cb + 256;
      async_cp16(x + (size_t)(tok0 + 2 * w) * D + nb + lane * 4,
                 (void*)&xbuf[cur ^ 1][2 * w][0]);
      async_cp16(x + (size_t)(tok0 + 2 * w + 1) * D + nb + lane * 4,
                 (void*)&xbuf[cur ^ 1][2 * w + 1][0]);
    }
    float4 w4[6];
#pragma unroll
    for (int g = 0; g < 6; ++g) w4[g] = *(const float4*)(Wp[g] + cb + lane * 4);
    float4 r4 = *(const float4*)(rms_w + cb + lane * 4);
#pragma unroll
    for (int t = 0; t < 8; ++t) {
      float4 xv = *(const float4*)(&xbuf[cur][t][lane * 4]);
      float ss = xv.x * xv.x + xv.y * xv.y + xv.z * xv.z + xv.w * xv.w;
      if ((t >> 1) == w) { if (t & 1) sq1 += ss; else sq0 += ss; }
      float4 xr;
      xr.x = xv.x * r4.x; xr.y = xv.y * r4.y; xr.z = xv.z * r4.z; xr.w = xv.w * r4.w;
#pragma unroll
      for (int g = 0; g < 6; ++g)
        acc[g][t] += xr.x * w4[g].x + xr.y * w4[g].y + xr.z * w4[g].z + xr.w * w4[g].w;
    }
    __syncthreads();   // drains prefetch (vmcnt0) + guards buffer swap
  }

  // wave reductions -> LDS
#pragma unroll
  for (int g = 0; g < 6; ++g)
#pragma unroll
    for (int t = 0; t < 8; ++t) {
      float v = acc[g][t];
      for (int off = 32; off > 0; off >>= 1) v += __shfl_xor(v, off, 64);
      if (lane == 0) logits_lds[t][w * 6 + g] = v;
    }
  {
    float v0 = sq0, v1 = sq1;
    for (int off = 32; off > 0; off >>= 1) {
      v0 += __shfl_xor(v0, off, 64);
      v1 += __shfl_xor(v1, off, 64);
    }
    if (lane == 0) { sq_lds[w * 2] = v0; sq_lds[w * 2 + 1] = v1; }
  }
  __syncthreads();

  // per-token cheap scalar math (threads 0..7): rms scale + sigmoids
  if (tid < 8) {
    const int t = tid;
    float s = rsqrtf(sq_lds[t] * (1.0f / 4096.0f) + 1e-8f);
    s_lds[t] = s;
    float a_pre = apre[0], a_post = apost[0];

    float hp[4];
    float sum_p = 1e-6f;
#pragma unroll
    for (int i = 0; i < 4; ++i) {
      float z = a_pre * (s * logits_lds[t][i]) + bpre[i];
      hp[i] = 1.0f / (1.0f + __expf(-z));
      sum_p += hp[i];
    }
    float inv_p = 1.0f / sum_p;
#pragma unroll
    for (int i = 0; i < 4; ++i) hpre_lds[t][i] = hp[i] * inv_p;

    float* go = gates_out + (size_t)(tok0 + t) * 20;
    float hq[4];
    float sum_q = 1e-6f;
#pragma unroll
    for (int i = 0; i < 4; ++i) {
      float z = a_post * (s * logits_lds[t][4 + i]) + bpost[i];
      hq[i] = 2.0f / (1.0f + __expf(-z));
      sum_q += hq[i];
    }
    float inv_q = 1.0f / sum_q;
#pragma unroll
    for (int i = 0; i < 4; ++i) go[i] = hq[i] * inv_q;
  }
  __syncthreads();

  // phase B: x_layer[t][c] = sum_i hpre_w[i] * x[t][i*1024+c]  (bf16 out)
#pragma unroll
  for (int t = 0; t < 8; ++t) {
    float h0 = hpre_lds[t][0], h1 = hpre_lds[t][1];
    float h2 = hpre_lds[t][2], h3 = hpre_lds[t][3];
    const size_t base = (size_t)(tok0 + t) * D;
    float4 x0 = *(const float4*)(x + base + 0 * CH + tid * 4);
    float4 x1 = *(const float4*)(x + base + 1 * CH + tid * 4);
    float4 x2 = *(const float4*)(x + base + 2 * CH + tid * 4);
    float4 x3 = *(const float4*)(x + base + 3 * CH + tid * 4);
    ushort4v o;
    o.x = f2bf(h0 * x0.x + h1 * x1.x + h2 * x2.x + h3 * x3.x);
    o.y = f2bf(h0 * x0.y + h1 * x1.y + h2 * x2.y + h3 * x3.y);
    o.z = f2bf(h0 * x0.z + h1 * x1.z + h2 * x2.z + h3 * x3.z);
    o.w = f2bf(h0 * x0.w + h1 * x1.w + h2 * x2.w + h3 * x3.w);
    *(ushort4v*)(xlayer + (size_t)(tok0 + t) * CH + tid * 4) = o;
  }

  // sinkhorn, parallel over 32 lanes (8 tokens x 4 rows), runs last so the
  // other 3 waves retire and the dependent-chain tail overlaps other blocks
  if (tid < 32) {
    const int t = tid >> 2;
    const int r = tid & 3;
    const float s = s_lds[t];
    const float a_res = ares[0];
    float Zrow[4], Zcol[4];
#pragma unroll
    for (int j = 0; j < 4; ++j) {
      Zrow[j] = (a_res * (s * logits_lds[t][8 + r * 4 + j]) + bres[r * 4 + j]) * 20.0f;
      Zcol[j] = (a_res * (s * logits_lds[t][8 + j * 4 + r]) + bres[j * 4 + r]) * 20.0f;
    }
    float u = 0.f, v = 0.f;
    const int base = t << 2;
    for (int it = 0; it < 20; ++it) {
      float v0 = __shfl(v, base + 0, 64), v1 = __shfl(v, base + 1, 64);
      float v2 = __shfl(v, base + 2, 64), v3 = __shfl(v, base + 3, 64);
      float a0 = Zrow[0] + v0, a1 = Zrow[1] + v1, a2 = Zrow[2] + v2, a3 = Zrow[3] + v3;
      float m = fmaxf(fmaxf(a0, a1), fmaxf(a2, a3));
      float sm = __expf(a0 - m) + __expf(a1 - m) + __expf(a2 - m) + __expf(a3 - m);
      u = -(m + __logf(sm));
      float u0 = __shfl(u, base + 0, 64), u1 = __shfl(u, base + 1, 64);
      float u2 = __shfl(u, base + 2, 64), u3 = __shfl(u, base + 3, 64);
      float b0 = Zcol[0] + u0, b1 = Zcol[1] + u1, b2 = Zcol[2] + u2, b3 = Zcol[3] + u3;
      float m2 = fmaxf(fmaxf(b0, b1), fmaxf(b2, b3));
      float sm2 = __expf(b0 - m2) + __expf(b1 - m2) + __expf(b2 - m2) + __expf(b3 - m2);
      v = -(m2 + __logf(sm2));
    }
    float v0 = __shfl(v, base + 0, 64), v1 = __shfl(v, base + 1, 64);
    float v2 = __shfl(v, base + 2, 64), v3 = __shfl(v, base + 3, 64);
    float* go = gates_out + (size_t)(tok0 + t) * 20;
    go[4 + r * 4 + 0] = __expf(Zrow[0] + u + v0);
    go[4 + r * 4 + 1] = __expf(Zrow[1] + u + v1);
    go[4 + r * 4 + 2] = __expf(Zrow[2] + u + v2);
    go[4 + r * 4 + 3] = __expf(Zrow[3] + u + v3);
  }
}

// ---------------------------------------------------------------------------
// Kernel 2: y = x_layer @ W_sub^T (bf16 MFMA, 128x128 tile, BK=64, dbuf)
//           epilogue: y -> LDS transpose -> fully-coalesced float4 mixing
// ---------------------------------------------------------------------------
__global__ __launch_bounds__(256) void gemm_epi(
    const unsigned short* __restrict__ A,   // x_layer bf16 [8192][1024]
    const unsigned short* __restrict__ B,   // W_sub  bf16 [1024][1024]
    const float* __restrict__ x,            // x_streams fp32
    const float* __restrict__ gates,        // [8192][20]: Hpost_w[4], Hres[16]
    float* __restrict__ out) {
  // union: staging dbuf (64 KB) reused as padded y-tile (128x132 f32, 67.6 KB)
  __shared__ __align__(16) char lds_raw[128 * 132 * 4];
  __shared__ float gsm[128 * 20];
  unsigned short* stg = (unsigned short*)lds_raw;   // [buf][A|B][128*64]
  float* ybuf = (float*)lds_raw;

  const int tid = threadIdx.x;
  const int lane = tid & 63;
  const int w = tid >> 6;
  const int n0 = blockIdx.x * 128;
  const int m0 = blockIdx.y * 128;

  for (int i = tid; i < 128 * 20; i += 256) gsm[i] = gates[(size_t)m0 * 20 + i];

  float4v accf[4][4];
#pragma unroll
  for (int mi = 0; mi < 4; ++mi)
#pragma unroll
    for (int ni = 0; ni < 4; ++ni) {
      accf[mi][ni].x = 0.f; accf[mi][ni].y = 0.f;
      accf[mi][ni].z = 0.f; accf[mi][ni].w = 0.f;
    }

  const int wm = (w >> 1) * 64;
  const int wn = (w & 1) * 64;
  const int srow = lane >> 3;   // staging: 8 rows per 1KB chunk
  const int sslot = lane & 7;   // 8 x 16B slots per 128B row

  // stage(kt, buf): A/B tile 128x64 bf16 each, XOR-swizzled k-quads
#define STAGE(KT, BUF)                                                        \
  {                                                                           \
    const int k0s = (KT) * 64;                                                \
    unsigned short* As = stg + (BUF) * 8192;                                  \
    unsigned short* Bs = stg + 16384 + (BUF) * 8192;                          \
    _Pragma("unroll")                                                         \
    for (int i = 0; i < 4; ++i) {                                             \
      int chunk = w * 4 + i;                                                  \
      int row = chunk * 8 + srow;                                             \
      int qg = sslot ^ (row & 7);                                             \
      async_cp16(A + (size_t)(m0 + row) * 1024 + k0s + qg * 8,                \
                 (void*)(As + chunk * 512));                                  \
      async_cp16(B + (size_t)(n0 + row) * 1024 + k0s + qg * 8,                \
                 (void*)(Bs + chunk * 512));                                  \
    }                                                                         \
  }

  STAGE(0, 0);
  __syncthreads();

  for (int kt = 0; kt < 16; ++kt) {
    const int cur = kt & 1;
    if (kt < 15) STAGE(kt + 1, cur ^ 1);
    const unsigned short* As = stg + cur * 8192;
    const unsigned short* Bs = stg + 16384 + cur * 8192;
#pragma unroll
    for (int kk = 0; kk < 2; ++kk) {
      short8v a[4], b[4];
#pragma unroll
      for (int mi = 0; mi < 4; ++mi) {
        int row = wm + mi * 16 + (lane & 15);
        int q = (kk * 4 + (lane >> 4)) ^ (row & 7);
        a[mi] = *(const short8v*)(As + row * 64 + q * 8);
      }
#pragma unroll
      for (int ni = 0; ni < 4; ++ni) {
        int row = wn + ni * 16 + (lane & 15);
        int q = (kk * 4 + (lane >> 4)) ^ (row & 7);
        b[ni] = *(const short8v*)(Bs + row * 64 + q * 8);
      }
#pragma unroll
      for (int mi = 0; mi < 4; ++mi)
#pragma unroll
        for (int ni = 0; ni < 4; ++ni)
          accf[mi][ni] = __builtin_amdgcn_mfma_f32_16x16x32_bf16(
              a[mi], b[ni], accf[mi][ni], 0, 0, 0);
    }
    __syncthreads();   // drains prefetch + guards buffer swap
  }

  // write y tile to LDS (padded stride 132 -> no 4-way bank conflict)
#pragma unroll
  for (int mi = 0; mi < 4; ++mi)
#pragma unroll
    for (int ni = 0; ni < 4; ++ni)
#pragma unroll
      for (int r = 0; r < 4; ++r) {
        int row = wm + mi * 16 + (lane >> 4) * 4 + r;
        int col = wn + ni * 16 + (lane & 15);
        ybuf[row * 132 + col] = accf[mi][ni][r];
      }
  __syncthreads();

  // fully-coalesced epilogue: 16B/lane loads+stores
#pragma unroll 4
  for (int i = 0; i < 16; ++i) {
    int idx = i * 256 + tid;        // 0..4095 float4 slots
    int tl = idx >> 5;              // token row 0..127
    int c4 = idx & 31;              // float4 column 0..31
    const size_t t = (size_t)(m0 + tl);
    const float* gp = gsm + tl * 20;
    float4 y4 = *(const float4*)&ybuf[tl * 132 + c4 * 4];
    const size_t xb = t * 4096 + n0 + c4 * 4;
    float4 x0 = *(const float4*)(x + xb);
    float4 x1 = *(const float4*)(x + xb + 1024);
    float4 x2 = *(const float4*)(x + xb + 2048);
    float4 x3 = *(const float4*)(x + xb + 3072);
#pragma unroll
    for (int o = 0; o < 4; ++o) {
      float h0 = gp[4 + o * 4 + 0], h1 = gp[4 + o * 4 + 1];
      float h2 = gp[4 + o * 4 + 2], h3 = gp[4 + o * 4 + 3];
      float hp = gp[o];
      float4 rr;
      rr.x = x0.x * h0 + x1.x * h1 + x2.x * h2 + x3.x * h3 + hp * y4.x;
      rr.y = x0.y * h0 + x1.y * h1 + x2.y * h2 + x3.y * h3 + hp * y4.y;
      rr.z = x0.z * h0 + x1.z * h1 + x2.z * h2 + x3.z * h3 + hp * y4.z;
      rr.w = x0.w * h0 + x1.w * h1 + x2.w * h2 + x3.w * h3 + hp * y4.w;
      *(float4*)(out + t * 4096 + (size_t)o * 1024 + n0 + c4 * 4) = rr;
    }
  }
}

extern "C" void kernel_launch(void* const* d_in, const int* in_sizes, int n_in,
                              void* d_out, int out_size, void* d_ws, size_t ws_size,
                              hipStream_t stream) {
  const float* x     = (const float*)d_in[0];
  const float* rms_w = (const float*)d_in[1];
  const float* Wpre  = (const float*)d_in[2];
  const float* Wpost = (const float*)d_in[3];
  const float* Wres  = (const float*)d_in[4];
  const float* bpre  = (const float*)d_in[5];
  const float* bpost = (const float*)d_in[6];
  const float* bres  = (const float*)d_in[7];
  const float* apre  = (const float*)d_in[8];
  const float* apost = (const float*)d_in[9];
  const float* ares  = (const float*)d_in[10];
  const float* Wsub  = (const float*)d_in[11];
  float* out = (float*)d_out;

  char* ws = (char*)d_ws;
  float* gates           = (float*)ws;                         // 640 KB
  unsigned short* Wb     = (unsigned short*)(ws + (1 << 20));  // 2 MB
  unsigned short* xlayer = (unsigned short*)(ws + (4 << 20));  // 16 MB

  prep_wsub<<<1024, 256, 0, stream>>>(Wsub, Wb);
  gates_kernel<<<1024, 256, 0, stream>>>(x, rms_w, Wpre, Wpost, Wres, bpre,
                                         bpost, bres, apre, apost, ares,
                                         gates, xlayer);
  gemm_epi<<<dim3(8, 64), 256, 0, stream>>>(xlayer, Wb, x, gates, out);
}

// Round 3
// 381.715 us; speedup vs baseline: 1.1190x; 1.1123x over previous
//
#include <hip/hip_runtime.h>

#define NTOK 8192
#define D 4096
#define CH 1024

typedef __attribute__((ext_vector_type(8))) short short8v;
typedef __attribute__((ext_vector_type(4))) float float4v;
typedef __attribute__((ext_vector_type(4))) unsigned short ushort4v;

static __device__ __forceinline__ unsigned short f2bf(float f) {
  unsigned int u = __float_as_uint(f);
  u += 0x7fff + ((u >> 16) & 1);   // round-to-nearest-even
  return (unsigned short)(u >> 16);
}

static __device__ __forceinline__ void async_cp16(const void* g, void* l) {
  __builtin_amdgcn_global_load_lds((__attribute__((address_space(1))) void*)g,
                                   (__attribute__((address_space(3))) void*)l,
                                   16, 0, 0);
}

// ---------------------------------------------------------------------------
// Kernel 1: gates (rms + 24 projections + sinkhorn) + x_layer (bf16)
//           + W_sub fp32->bf16 conversion folded in (1 KB per block).
// 8 tokens per block, 512 threads = 8 waves. Wave w owns 3 gate rows and
// stages/sumsq's token w. Double-buffered async x staging, 1 barrier/chunk.
// ---------------------------------------------------------------------------
__global__ __launch_bounds__(512) void gates_kernel(
    const float* __restrict__ x, const float* __restrict__ rms_w,
    const float* __restrict__ Wpre, const float* __restrict__ Wpost,
    const float* __restrict__ Wres, const float* __restrict__ bpre,
    const float* __restrict__ bpost, const float* __restrict__ bres,
    const float* __restrict__ apre, const float* __restrict__ apost,
    const float* __restrict__ ares, const float* __restrict__ Wsub,
    unsigned short* __restrict__ Wb, float* __restrict__ gates_out,
    unsigned short* __restrict__ xlayer) {
  __shared__ float xbuf[2][8][256];     // 16 KB double buffer
  __shared__ float logits_lds[8][24];
  __shared__ float sq_lds[8];
  __shared__ float s_lds[8];
  __shared__ float hpre_lds[8][4];

  const int tid = threadIdx.x;
  const int lane = tid & 63;
  const int w = tid >> 6;               // 0..7
  const int tok0 = blockIdx.x * 8;

  // fold prep_wsub: this block converts Wsub[blockIdx*1024 .. +1024) to bf16
  {
    int i = blockIdx.x * 1024 + tid * 2;
    float2 v = *(const float2*)(Wsub + i);
    unsigned int packed = (unsigned int)f2bf(v.x) | ((unsigned int)f2bf(v.y) << 16);
    *(unsigned int*)(Wb + i) = packed;
  }

  const float* Wp[3];
#pragma unroll
  for (int g = 0; g < 3; ++g) {
    int gg = w * 3 + g;
    Wp[g] = (gg < 4) ? (Wpre + gg * D)
          : (gg < 8) ? (Wpost + (gg - 4) * D)
                     : (Wres + (gg - 8) * D);
  }

  float acc[3][8];
#pragma unroll
  for (int g = 0; g < 3; ++g)
#pragma unroll
    for (int t = 0; t < 8; ++t) acc[g][t] = 0.f;
  float sq = 0.f;

  // prologue: wave w stages token w chunk 0 (1 KB = 64 lanes x 16 B)
  async_cp16(x + (size_t)(tok0 + w) * D + lane * 4, (void*)&xbuf[0][w][0]);
  __syncthreads();

  for (int chk = 0; chk < 16; ++chk) {
    const int cb = chk * 256;
    const int cur = chk & 1;
    if (chk < 15)
      async_cp16(x + (size_t)(tok0 + w) * D + cb + 256 + lane * 4,
                 (void*)&xbuf[cur ^ 1][w][0]);
    float4 w4[3];
#pragma unroll
    for (int g = 0; g < 3; ++g) w4[g] = *(const float4*)(Wp[g] + cb + lane * 4);
    float4 r4 = *(const float4*)(rms_w + cb + lane * 4);
#pragma unroll
    for (int t = 0; t < 8; ++t) {
      float4 xv = *(const float4*)(&xbuf[cur][t][lane * 4]);
      if (t == w)
        sq += xv.x * xv.x + xv.y * xv.y + xv.z * xv.z + xv.w * xv.w;
      float4 xr;
      xr.x = xv.x * r4.x; xr.y = xv.y * r4.y; xr.z = xv.z * r4.z; xr.w = xv.w * r4.w;
#pragma unroll
      for (int g = 0; g < 3; ++g)
        acc[g][t] += xr.x * w4[g].x + xr.y * w4[g].y + xr.z * w4[g].z + xr.w * w4[g].w;
    }
    __syncthreads();
  }

  // wave reductions -> LDS (wave w: 3 gate rows x 8 tokens + token w sumsq)
#pragma unroll
  for (int g = 0; g < 3; ++g)
#pragma unroll
    for (int t = 0; t < 8; ++t) {
      float v = acc[g][t];
      for (int off = 32; off > 0; off >>= 1) v += __shfl_xor(v, off, 64);
      if (lane == 0) logits_lds[t][w * 3 + g] = v;
    }
  {
    float v = sq;
    for (int off = 32; off > 0; off >>= 1) v += __shfl_xor(v, off, 64);
    if (lane == 0) sq_lds[w] = v;
  }
  __syncthreads();

  // per-token cheap scalar math (threads 0..7): rms scale + sigmoids
  if (tid < 8) {
    const int t = tid;
    float s = rsqrtf(sq_lds[t] * (1.0f / 4096.0f) + 1e-8f);
    s_lds[t] = s;
    float a_pre = apre[0], a_post = apost[0];

    float hp[4];
    float sum_p = 1e-6f;
#pragma unroll
    for (int i = 0; i < 4; ++i) {
      float z = a_pre * (s * logits_lds[t][i]) + bpre[i];
      hp[i] = 1.0f / (1.0f + __expf(-z));
      sum_p += hp[i];
    }
    float inv_p = 1.0f / sum_p;
#pragma unroll
    for (int i = 0; i < 4; ++i) hpre_lds[t][i] = hp[i] * inv_p;

    float* go = gates_out + (size_t)(tok0 + t) * 20;
    float hq[4];
    float sum_q = 1e-6f;
#pragma unroll
    for (int i = 0; i < 4; ++i) {
      float z = a_post * (s * logits_lds[t][4 + i]) + bpost[i];
      hq[i] = 2.0f / (1.0f + __expf(-z));
      sum_q += hq[i];
    }
    float inv_q = 1.0f / sum_q;
#pragma unroll
    for (int i = 0; i < 4; ++i) go[i] = hq[i] * inv_q;
  }
  __syncthreads();

  // phase B: x_layer[t][c] = sum_i hpre_w[i] * x[t][i*1024+c]  (bf16 out)
  {
    const int col = (tid & 255) * 4;    // channel within stream
    const int half = tid >> 8;          // 0..1
#pragma unroll
    for (int r = 0; r < 4; ++r) {
      const int t = r * 2 + half;
      float h0 = hpre_lds[t][0], h1 = hpre_lds[t][1];
      float h2 = hpre_lds[t][2], h3 = hpre_lds[t][3];
      const size_t base = (size_t)(tok0 + t) * D;
      float4 x0 = *(const float4*)(x + base + 0 * CH + col);
      float4 x1 = *(const float4*)(x + base + 1 * CH + col);
      float4 x2 = *(const float4*)(x + base + 2 * CH + col);
      float4 x3 = *(const float4*)(x + base + 3 * CH + col);
      ushort4v o;
      o.x = f2bf(h0 * x0.x + h1 * x1.x + h2 * x2.x + h3 * x3.x);
      o.y = f2bf(h0 * x0.y + h1 * x1.y + h2 * x2.y + h3 * x3.y);
      o.z = f2bf(h0 * x0.z + h1 * x1.z + h2 * x2.z + h3 * x3.z);
      o.w = f2bf(h0 * x0.w + h1 * x1.w + h2 * x2.w + h3 * x3.w);
      *(ushort4v*)(xlayer + (size_t)(tok0 + t) * CH + col) = o;
    }
  }

  // sinkhorn, parallel over 32 lanes (8 tokens x 4 rows), wave 0 only; runs
  // last so waves 1..7 retire and the dependent-chain tail overlaps blocks
  if (tid < 32) {
    const int t = tid >> 2;
    const int r = tid & 3;
    const float s = s_lds[t];
    const float a_res = ares[0];
    float Zrow[4], Zcol[4];
#pragma unroll
    for (int j = 0; j < 4; ++j) {
      Zrow[j] = (a_res * (s * logits_lds[t][8 + r * 4 + j]) + bres[r * 4 + j]) * 20.0f;
      Zcol[j] = (a_res * (s * logits_lds[t][8 + j * 4 + r]) + bres[j * 4 + r]) * 20.0f;
    }
    float u = 0.f, v = 0.f;
    const int base = t << 2;
    for (int it = 0; it < 20; ++it) {
      float v0 = __shfl(v, base + 0, 64), v1 = __shfl(v, base + 1, 64);
      float v2 = __shfl(v, base + 2, 64), v3 = __shfl(v, base + 3, 64);
      float a0 = Zrow[0] + v0, a1 = Zrow[1] + v1, a2 = Zrow[2] + v2, a3 = Zrow[3] + v3;
      float m = fmaxf(fmaxf(a0, a1), fmaxf(a2, a3));
      float sm = __expf(a0 - m) + __expf(a1 - m) + __expf(a2 - m) + __expf(a3 - m);
      u = -(m + __logf(sm));
      float u0 = __shfl(u, base + 0, 64), u1 = __shfl(u, base + 1, 64);
      float u2 = __shfl(u, base + 2, 64), u3 = __shfl(u, base + 3, 64);
      float b0 = Zcol[0] + u0, b1 = Zcol[1] + u1, b2 = Zcol[2] + u2, b3 = Zcol[3] + u3;
      float m2 = fmaxf(fmaxf(b0, b1), fmaxf(b2, b3));
      float sm2 = __expf(b0 - m2) + __expf(b1 - m2) + __expf(b2 - m2) + __expf(b3 - m2);
      v = -(m2 + __logf(sm2));
    }
    float v0 = __shfl(v, base + 0, 64), v1 = __shfl(v, base + 1, 64);
    float v2 = __shfl(v, base + 2, 64), v3 = __shfl(v, base + 3, 64);
    float* go = gates_out + (size_t)(tok0 + t) * 20;
    go[4 + r * 4 + 0] = __expf(Zrow[0] + u + v0);
    go[4 + r * 4 + 1] = __expf(Zrow[1] + u + v1);
    go[4 + r * 4 + 2] = __expf(Zrow[2] + u + v2);
    go[4 + r * 4 + 3] = __expf(Zrow[3] + u + v3);
  }
}

// ---------------------------------------------------------------------------
// Kernel 2: y = x_layer @ W_sub^T (bf16 MFMA, 128x128 tile, BK=64, dbuf)
//           epilogue: y -> LDS transpose -> fully-coalesced float4 mixing
// ---------------------------------------------------------------------------
__global__ __launch_bounds__(256) void gemm_epi(
    const unsigned short* __restrict__ A,   // x_layer bf16 [8192][1024]
    const unsigned short* __restrict__ B,   // W_sub  bf16 [1024][1024]
    const float* __restrict__ x,            // x_streams fp32
    const float* __restrict__ gates,        // [8192][20]: Hpost_w[4], Hres[16]
    float* __restrict__ out) {
  // union: staging dbuf (64 KB) reused as padded y-tile (128x132 f32, 67.6 KB)
  __shared__ __align__(16) char lds_raw[128 * 132 * 4];
  __shared__ float gsm[128 * 20];
  unsigned short* stg = (unsigned short*)lds_raw;   // [buf][A|B][128*64]
  float* ybuf = (float*)lds_raw;

  const int tid = threadIdx.x;
  const int lane = tid & 63;
  const int w = tid >> 6;
  const int n0 = blockIdx.x * 128;
  const int m0 = blockIdx.y * 128;

  for (int i = tid; i < 128 * 20; i += 256) gsm[i] = gates[(size_t)m0 * 20 + i];

  float4v accf[4][4];
#pragma unroll
  for (int mi = 0; mi < 4; ++mi)
#pragma unroll
    for (int ni = 0; ni < 4; ++ni) {
      accf[mi][ni].x = 0.f; accf[mi][ni].y = 0.f;
      accf[mi][ni].z = 0.f; accf[mi][ni].w = 0.f;
    }

  const int wm = (w >> 1) * 64;
  const int wn = (w & 1) * 64;
  const int srow = lane >> 3;   // staging: 8 rows per 1KB chunk
  const int sslot = lane & 7;   // 8 x 16B slots per 128B row

#define STAGE(KT, BUF)                                                        \
  {                                                                           \
    const int k0s = (KT) * 64;                                                \
    unsigned short* As = stg + (BUF) * 8192;                                  \
    unsigned short* Bs = stg + 16384 + (BUF) * 8192;                          \
    _Pragma("unroll")                                                         \
    for (int i = 0; i < 4; ++i) {                                             \
      int chunk = w * 4 + i;                                                  \
      int row = chunk * 8 + srow;                                             \
      int qg = sslot ^ (row & 7);                                             \
      async_cp16(A + (size_t)(m0 + row) * 1024 + k0s + qg * 8,                \
                 (void*)(As + chunk * 512));                                  \
      async_cp16(B + (size_t)(n0 + row) * 1024 + k0s + qg * 8,                \
                 (void*)(Bs + chunk * 512));                                  \
    }                                                                         \
  }

  STAGE(0, 0);
  __syncthreads();

  for (int kt = 0; kt < 16; ++kt) {
    const int cur = kt & 1;
    if (kt < 15) STAGE(kt + 1, cur ^ 1);
    const unsigned short* As = stg + cur * 8192;
    const unsigned short* Bs = stg + 16384 + cur * 8192;
#pragma unroll
    for (int kk = 0; kk < 2; ++kk) {
      short8v a[4], b[4];
#pragma unroll
      for (int mi = 0; mi < 4; ++mi) {
        int row = wm + mi * 16 + (lane & 15);
        int q = (kk * 4 + (lane >> 4)) ^ (row & 7);
        a[mi] = *(const short8v*)(As + row * 64 + q * 8);
      }
#pragma unroll
      for (int ni = 0; ni < 4; ++ni) {
        int row = wn + ni * 16 + (lane & 15);
        int q = (kk * 4 + (lane >> 4)) ^ (row & 7);
        b[ni] = *(const short8v*)(Bs + row * 64 + q * 8);
      }
#pragma unroll
      for (int mi = 0; mi < 4; ++mi)
#pragma unroll
        for (int ni = 0; ni < 4; ++ni)
          accf[mi][ni] = __builtin_amdgcn_mfma_f32_16x16x32_bf16(
              a[mi], b[ni], accf[mi][ni], 0, 0, 0);
    }
    __syncthreads();
  }

  // write y tile to LDS (padded stride 132 -> no 4-way bank conflict)
#pragma unroll
  for (int mi = 0; mi < 4; ++mi)
#pragma unroll
    for (int ni = 0; ni < 4; ++ni)
#pragma unroll
      for (int r = 0; r < 4; ++r) {
        int row = wm + mi * 16 + (lane >> 4) * 4 + r;
        int col = wn + ni * 16 + (lane & 15);
        ybuf[row * 132 + col] = accf[mi][ni][r];
      }
  __syncthreads();

  // fully-coalesced epilogue: 16B/lane loads+stores
#pragma unroll 4
  for (int i = 0; i < 16; ++i) {
    int idx = i * 256 + tid;        // 0..4095 float4 slots
    int tl = idx >> 5;              // token row 0..127
    int c4 = idx & 31;              // float4 column 0..31
    const size_t t = (size_t)(m0 + tl);
    const float* gp = gsm + tl * 20;
    float4 y4 = *(const float4*)&ybuf[tl * 132 + c4 * 4];
    const size_t xb = t * 4096 + n0 + c4 * 4;
    float4 x0 = *(const float4*)(x + xb);
    float4 x1 = *(const float4*)(x + xb + 1024);
    float4 x2 = *(const float4*)(x + xb + 2048);
    float4 x3 = *(const float4*)(x + xb + 3072);
#pragma unroll
    for (int o = 0; o < 4; ++o) {
      float h0 = gp[4 + o * 4 + 0], h1 = gp[4 + o * 4 + 1];
      float h2 = gp[4 + o * 4 + 2], h3 = gp[4 + o * 4 + 3];
      float hp = gp[o];
      float4 rr;
      rr.x = x0.x * h0 + x1.x * h1 + x2.x * h2 + x3.x * h3 + hp * y4.x;
      rr.y = x0.y * h0 + x1.y * h1 + x2.y * h2 + x3.y * h3 + hp * y4.y;
      rr.z = x0.z * h0 + x1.z * h1 + x2.z * h2 + x3.z * h3 + hp * y4.z;
      rr.w = x0.w * h0 + x1.w * h1 + x2.w * h2 + x3.w * h3 + hp * y4.w;
      *(float4*)(out + t * 4096 + (size_t)o * 1024 + n0 + c4 * 4) = rr;
    }
  }
}

extern "C" void kernel_launch(void* const* d_in, const int* in_sizes, int n_in,
                              void* d_out, int out_size, void* d_ws, size_t ws_size,
                              hipStream_t stream) {
  const float* x     = (const float*)d_in[0];
  const float* rms_w = (const float*)d_in[1];
  const float* Wpre  = (const float*)d_in[2];
  const float* Wpost = (const float*)d_in[3];
  const float* Wres  = (const float*)d_in[4];
  const float* bpre  = (const float*)d_in[5];
  const float* bpost = (const float*)d_in[6];
  const float* bres  = (const float*)d_in[7];
  const float* apre  = (const float*)d_in[8];
  const float* apost = (const float*)d_in[9];
  const float* ares  = (const float*)d_in[10];
  const float* Wsub  = (const float*)d_in[11];
  float* out = (float*)d_out;

  char* ws = (char*)d_ws;
  float* gates           = (float*)ws;                         // 640 KB
  unsigned short* Wb     = (unsigned short*)(ws + (1 << 20));  // 2 MB
  unsigned short* xlayer = (unsigned short*)(ws + (4 << 20));  // 16 MB

  gates_kernel<<<1024, 512, 0, stream>>>(x, rms_w, Wpre, Wpost, Wres, bpre,
                                         bpost, bres, apre, apost, ares,
                                         Wsub, Wb, gates, xlayer);
  gemm_epi<<<dim3(8, 64), 256, 0, stream>>>(xlayer, Wb, x, gates, out);
}